// Round 8
// baseline (402.404 us; speedup 1.0000x reference)
//
#include <hip/hip_runtime.h>
#include <stdint.h>
#include <math.h>

#define LRES 8192
#define KNB  48
#define ASTR 296   // f16 row stride for A (148 words: only 2-way bank aliasing = free)
#define CUT  64    // knn: histogram only bins < CUT (16 Angstrom); exact fallback if b* >= CUT-1

typedef _Float16 half_t;
typedef _Float16 half8 __attribute__((ext_vector_type(8)));
typedef float f4 __attribute__((ext_vector_type(4)));

// ---------------- setup_a: weight reorder/convert (writes Wh32) ----------------
// MUST be a separate launch from setup_b: hbias reads Wh32, and intra-grid block
// ordering is undefined (r7 race: absmax 1.95 from hbias blocks racing prep blocks).
__global__ __launch_bounds__(256) void setup_a_kernel(
    const float* __restrict__ We, const float* __restrict__ Wproj,
    const float* __restrict__ Wpos,
    half_t* __restrict__ WeH, half_t* __restrict__ WpH,
    float* __restrict__ Wh32, half_t* __restrict__ WposB) {
  int t = blockIdx.x * blockDim.x + threadIdx.x;
  if (t < 128 * 288) {
    int n = t / 288, kp = t % 288;
    int k = kp < 160 ? kp : kp + 128;
    WeH[n * 288 + kp] = (half_t)We[n * 416 + k];
  }
  if (t < 128 * 128) {
    int n = t >> 7, k = t & 127;
    WpH[t] = (half_t)Wproj[t];
    Wh32[k * 128 + n] = We[n * 416 + 160 + k];
  }
  if (t < 512) {
    int p = t >> 5, k = t & 31;
    float v = (k < 8) ? Wpos[p * 66 + 32 + k] : ((k < 16) ? 0.0f : Wpos[p * 66 + k]);
    WposB[t] = (half_t)v;
  }
}

// ---------------- setup_b: cvt (f32->f16 copies) + hbias GEMV (reads Wh32) ----------------
// blocks [0,1024): cvt; [1024,3072): hbias
__global__ __launch_bounds__(256) void setup_b_kernel(
    const float* __restrict__ f_node, const float* __restrict__ node_h,
    const float* __restrict__ Wh32,
    half_t* __restrict__ fnH, half_t* __restrict__ nhH,
    float* __restrict__ hb) {
  __shared__ float hrow[4][128];
  const int b = blockIdx.x;
  const int tid = threadIdx.x;
  if (b < 1024) {
    int g = b * 256 + tid;                         // 262144 chunks of 8 floats
    int sel = g >> 17;
    size_t off = (size_t)(g & 131071) * 8;
    const float* s = sel ? node_h : f_node;
    half_t* d = sel ? nhH : fnH;
    f4 a = *(const f4*)(s + off);
    f4 bb = *(const f4*)(s + off + 4);
    half8 h;
#pragma unroll
    for (int j = 0; j < 4; ++j) { h[j] = (half_t)a[j]; h[4 + j] = (half_t)bb[j]; }
    *(half8*)(d + off) = h;
  } else {
    const int i0 = (b - 1024) * 4;
    for (int u = tid; u < 512; u += 256) hrow[u >> 7][u & 127] = node_h[(size_t)i0 * 128 + u];
    __syncthreads();
    const int n = tid & 127, g = tid >> 7;
    float s0 = 0.f, s1 = 0.f;
#pragma unroll 8
    for (int cc = 0; cc < 128; ++cc) {
      float w = Wh32[cc * 128 + n];
      s0 = fmaf(w, hrow[g][cc], s0);
      s1 = fmaf(w, hrow[g + 2][cc], s1);
    }
    hb[(size_t)(i0 + g) * 128 + n] = s0;
    hb[(size_t)(i0 + g + 2) * 128 + n] = s1;
  }
}

// ---------------- fused kernel: knn (exact top-48) -> edge features + MFMA GEMMs + LN ----------------
// Block i selects its own 48 NN (identical algorithm to the proven split knn), drops (j, Dk)
// into LDS, then runs the edge phases. Cand arrays alias Ald (extracted before first Ald write).
// Resident blocks drift out of phase -> knn's VALU scan overlaps edge's MFMA on the same CU.
__global__ __launch_bounds__(256, 4) void fused_kernel(
    const float* __restrict__ X, const half_t* __restrict__ fnH,
    const half_t* __restrict__ nhH, const float* __restrict__ Wpos,
    const float* __restrict__ bpos, const float* __restrict__ ln_scale,
    const float* __restrict__ ln_bias, const float* __restrict__ bproj,
    const int* __restrict__ aatype, const int* __restrict__ residue_index,
    const half_t* __restrict__ WeH, const half_t* __restrict__ WpH,
    const half_t* __restrict__ WposB, const float* __restrict__ hbAll,
    float* __restrict__ out) {
  __shared__ __align__(16) half_t Ald[48 * ASTR];   // 28416 B; bytes [0,3072) alias knn cand arrays
  __shared__ float tabPool[672];   // pos_tab/aa_tab; aliased by redS/mean/rstd after P2
  __shared__ float DkL[48];
  __shared__ int jL[48], pidxL[48], aaL[48];
  __shared__ unsigned hist[256];
  __shared__ unsigned cnt;
  __shared__ int bstar_s;
  __shared__ unsigned cexp_s;
  __shared__ int needFull_s;

  double* candD = (double*)Ald;              // [256] = 2048 B
  int*    candJ = (int*)(Ald + 1024);        // [256] = 1024 B (half_t offset 1024 = byte 2048)
  float* pos_tab = tabPool;
  float* aa_tab  = tabPool + 256;
  float* redS    = tabPool;                  // aliases tabs after last tab read (P2)
  float* meanL   = tabPool + 384;
  float* rstdL   = tabPool + 432;

  const int i = blockIdx.x;
  const int tid = threadIdx.x;
  const int w = tid >> 6;
  const int lane = tid & 63;
  const int lm = lane & 15;
  const int quad = lane >> 4;
  const int quad8 = quad * 8;
  const int n0 = w * 32 + lm;

  // ---- weight tables (tabPool region: disjoint from knn's hist/cand) ----
  {
    int pp = tid >> 4, p = tid & 15;
    pos_tab[tid] = Wpos[p * 66 + pp] + bpos[p];
  }
  for (int t = tid; t < 416; t += 256) {
    int a = t >> 4, p = t & 15;
    aa_tab[t] = Wpos[p * 66 + 40 + a];
  }

  // ================= KNN phase =================
  const float xi = X[i * 3 + 0], yi = X[i * 3 + 1], zi = X[i * 3 + 2];
  hist[tid] = 0u;
  if (tid == 0) cnt = 0u;
  __syncthreads();
  unsigned bpack[8];
#pragma unroll
  for (int it = 0; it < 8; ++it) {
    int jb = (tid + it * 256) * 4;
    const float* xp = X + (size_t)jb * 3;
    f4 r0 = *(const f4*)(xp);
    f4 r1 = *(const f4*)(xp + 4);
    f4 r2 = *(const f4*)(xp + 8);
    float px[4] = {r0[0], r0[3], r1[2], r2[1]};
    float py[4] = {r0[1], r1[0], r1[3], r2[2]};
    float pz[4] = {r0[2], r1[1], r2[0], r2[3]};
#pragma unroll
    for (int q = 0; q < 4; ++q) {
      float dx = px[q] - xi, dy = py[q] - yi, dz = pz[q] - zi;
      float D = sqrtf(dx * dx + dy * dy + dz * dz + 1e-6f);
      int b = (int)(D * 4.0f); if (b > 255) b = 255;
      int idx = it * 4 + q;
      int sh = (idx & 3) * 8;
      if ((idx & 3) == 0) bpack[idx >> 2] = (unsigned)b; else bpack[idx >> 2] |= (unsigned)b << sh;
      if (b < CUT) atomicAdd(&hist[b], 1u);
    }
  }
  __syncthreads();
  if (tid == 0) {
    unsigned run = 0; int b = 0;
    while (b < 255 && run + hist[b] < KNB) { run += hist[b]; ++b; }
    bstar_s = b;
    needFull_s = (b >= CUT - 1) ? 1 : 0;
    unsigned tot = run + hist[b];
    if (b < 255) tot += hist[b + 1];
    cexp_s = tot;
  }
  __syncthreads();
  if (needFull_s) {           // rare: complete the histogram exactly, rescan
#pragma unroll
    for (int idx = 0; idx < 32; ++idx) {
      int b = (int)((bpack[idx >> 2] >> ((idx & 3) * 8)) & 0xFFu);
      if (b >= CUT) atomicAdd(&hist[b], 1u);
    }
    __syncthreads();
    if (tid == 0) {
      unsigned run = 0; int b = 0;
      while (b < 255 && run + hist[b] < KNB) { run += hist[b]; ++b; }
      bstar_s = b;
      unsigned tot = run + hist[b];
      if (b < 255) tot += hist[b + 1];
      cexp_s = tot;
    }
    __syncthreads();
  }
  int bthr = bstar_s + 1; if (bthr > 255) bthr = 255;
  const unsigned cexp = cexp_s;
  const double xid = (double)xi, yid = (double)yi, zid = (double)zi;
  {
    unsigned cmask = 0u;
#pragma unroll
    for (int idx = 0; idx < 32; ++idx) {
      int b = (int)((bpack[idx >> 2] >> ((idx & 3) * 8)) & 0xFFu);
      if (b <= bthr) cmask |= (1u << idx);
    }
    while (cmask) {
      int k = __builtin_ctz(cmask);
      cmask &= cmask - 1u;
      int j = (tid + (k >> 2) * 256) * 4 + (k & 3);
      unsigned p = atomicAdd(&cnt, 1u);
      if (p < 256u) {
        double ddx = (double)X[j * 3 + 0] - xid;
        double ddy = (double)X[j * 3 + 1] - yid;
        double ddz = (double)X[j * 3 + 2] - zid;
        candD[p] = sqrt(ddx * ddx + ddy * ddy + ddz * ddz + 1e-6);
        candJ[p] = j;
      }
    }
  }
  __syncthreads();
  unsigned nc = cnt;
  if (cexp <= 64u) {
    // common path: wave-0 register bitonic over 64 (double,int) keys -> jL/DkL
    if (tid < 64) {
      double d = (tid < (int)nc) ? candD[tid] : INFINITY;
      int j = (tid < (int)nc) ? candJ[tid] : 0x7FFFFFFF;
#pragma unroll
      for (int size = 2; size <= 64; size <<= 1) {
#pragma unroll
        for (int stride = 32; stride > 0; stride >>= 1) {
          if (stride >= size) continue;
          double dp = __shfl_xor(d, stride, 64);
          int jp = __shfl_xor(j, stride, 64);
          bool up = ((tid & size) == 0);
          bool lower = ((tid & stride) == 0);
          bool mine_gt = (d > dp) || (d == dp && j > jp);
          bool part_gt = (dp > d) || (dp == d && jp > j);
          bool keep = lower ? (mine_gt != up) : (part_gt != up);
          d = keep ? d : dp;
          j = keep ? j : jp;
        }
      }
      if (tid < KNB) { jL[tid] = j; DkL[tid] = (float)d; }
    }
  } else {
    // fallback (count in (64,256]): 256-way LDS bitonic (block-uniform branch)
    if (tid >= (int)nc) { candD[tid] = INFINITY; candJ[tid] = 0x7FFFFFFF; }
    __syncthreads();
    for (unsigned size = 2; size <= 256; size <<= 1) {
      for (unsigned stride = size >> 1; stride > 0; stride >>= 1) {
        unsigned partner = (unsigned)tid ^ stride;
        if (partner > (unsigned)tid) {
          double da = candD[tid], db = candD[partner];
          int ja = candJ[tid], jb = candJ[partner];
          bool agtb = (da > db) || (da == db && ja > jb);
          bool asc = ((tid & size) == 0);
          if (agtb == asc) {
            candD[tid] = db; candJ[tid] = jb;
            candD[partner] = da; candJ[partner] = ja;
          }
        }
        __syncthreads();
      }
    }
    if (tid < KNB) { jL[tid] = candJ[tid]; DkL[tid] = (float)candD[tid]; }
  }
  __syncthreads();   // knn results extracted; Ald (incl. cand alias region) free for edge

  // ================= EDGE phase (unchanged logic from r6) =================
  // ---- P0: per-edge scalars; geom into Ald cols 128..135 (f16) ----
  if (tid < KNB) {
    int e = tid;
    int j = jL[e];
    float Dk = DkL[e];
    float xj = X[j * 3 + 0], yj = X[j * 3 + 1], zj = X[j * 3 + 2];
    float inv = 1.0f / (Dk + 1e-6f);
    half_t* gr = Ald + e * ASTR + 128;
    gr[0] = (half_t)(Dk / 10.0f);
    gr[1] = (half_t)(1.0f / (1.0f + Dk));
    gr[2] = (half_t)expf(-Dk);
    gr[3] = (half_t)sinf(Dk);
    gr[4] = (half_t)cosf(Dk);
    gr[5] = (half_t)((xj - xi) * inv);
    gr[6] = (half_t)((yj - yi) * inv);
    gr[7] = (half_t)((zj - zi) * inv);
    // cols 136..143 MUST be zeroed: B rows 8..15 are zero, but 0*NaN-garbage = NaN in MFMA.
    *(uint2*)(gr + 8)  = (uint2){0u, 0u};
    *(uint2*)(gr + 12) = (uint2){0u, 0u};
    int off = residue_index[j] - residue_index[i] + 8;
    off = off < 0 ? 0 : (off > 15 ? 15 : off);
    pidxL[e] = off;
    aaL[e] = aatype[j];
  }
  __syncthreads();

  // ---- P1: rbf (cols 144..159) + half8 gathers fnH->0..127, nhH->160..287 ----
  for (int t = tid; t < KNB * 16; t += 256) {
    int e = t >> 4, m = t & 15;
    float z = (DkL[e] - (2.0f + (float)m * (20.0f / 15.0f))) * 0.8f;
    Ald[e * ASTR + 144 + m] = (half_t)expf(-z * z);
  }
#pragma unroll
  for (int it = 0; it < 6; ++it) {
    int cid = tid + it * 256;
    int e = cid >> 5, r = cid & 31;
    int sel = r >> 4, c8 = r & 15;
    const half_t* src = (sel ? nhH : fnH) + (size_t)jL[e] * 128 + c8 * 8;
    *(half8*)(Ald + e * ASTR + sel * 160 + c8 * 8) = *(const half8*)src;
  }
  // prefetch GEMM1 B + h_i bias; latency hidden under gathers/P2
  half8 bregA[9], bregB[9];
#pragma unroll
  for (int ks = 0; ks < 9; ++ks) {
    bregA[ks] = *(const half8*)(WeH + (size_t)n0 * 288 + ks * 32 + quad8);
    bregB[ks] = *(const half8*)(WeH + (size_t)(n0 + 16) * 288 + ks * 32 + quad8);
  }
  float hb0 = hbAll[(size_t)i * 128 + n0];
  float hb1 = hbAll[(size_t)i * 128 + n0 + 16];
  __syncthreads();

  // ---- P2: e_pos via single MFMA per wave + table adds ----
  if (w < 3) {
    half8 a = *(const half8*)(Ald + (w * 16 + lm) * ASTR + 128 + quad8);
    half8 bp = *(const half8*)(WposB + lm * 32 + quad8);
    f4 z = {};
    f4 ep = __builtin_amdgcn_mfma_f32_16x16x32_f16(a, bp, z, 0, 0, 0);
#pragma unroll
    for (int r = 0; r < 4; ++r) {
      int m = w * 16 + quad * 4 + r;
      float s = ep[r] + pos_tab[pidxL[m] * 16 + lm] + aa_tab[aaL[m] * 16 + lm];
      Ald[m * ASTR + 128 + lm] = (half_t)s;
    }
  }
  __syncthreads();

  // ---- GEMM1 ----
  f4 acc[3][2] = {};
#pragma unroll
  for (int ks = 0; ks < 9; ++ks) {
#pragma unroll
    for (int mt = 0; mt < 3; ++mt) {
      half8 a = *(const half8*)(Ald + (mt * 16 + lm) * ASTR + ks * 32 + quad8);
      acc[mt][0] = __builtin_amdgcn_mfma_f32_16x16x32_f16(a, bregA[ks], acc[mt][0], 0, 0, 0);
      acc[mt][1] = __builtin_amdgcn_mfma_f32_16x16x32_f16(a, bregB[ks], acc[mt][1], 0, 0, 0);
    }
  }
  // prefetch GEMM2 B + LN/proj params; latency hidden under LN reduce
  half8 b2A[4], b2B[4];
#pragma unroll
  for (int ks = 0; ks < 4; ++ks) {
    b2A[ks] = *(const half8*)(WpH + (size_t)n0 * 128 + ks * 32 + quad8);
    b2B[ks] = *(const half8*)(WpH + (size_t)(n0 + 16) * 128 + ks * 32 + quad8);
  }
  float ls0 = ln_scale[n0], ls1 = ln_scale[n0 + 16];
  float lb0 = ln_bias[n0],  lb1 = ln_bias[n0 + 16];
  float bp0 = bproj[n0],    bp1 = bproj[n0 + 16];

  // ---- h_i bias + LN partials ----
#pragma unroll
  for (int mt = 0; mt < 3; ++mt)
#pragma unroll
    for (int r = 0; r < 4; ++r) { acc[mt][0][r] += hb0; acc[mt][1][r] += hb1; }
#pragma unroll
  for (int mt = 0; mt < 3; ++mt)
#pragma unroll
    for (int r = 0; r < 4; ++r) {
      float e0 = acc[mt][0][r], e1 = acc[mt][1][r];
      float sv = e0 + e1;
      float qv = e0 * e0 + e1 * e1;
#pragma unroll
      for (int m = 1; m < 16; m <<= 1) {
        sv += __shfl_xor(sv, m, 16);
        qv += __shfl_xor(qv, m, 16);
      }
      if (lm == 0) {
        int row = mt * 16 + quad * 4 + r;
        redS[row * 8 + w * 2 + 0] = sv;
        redS[row * 8 + w * 2 + 1] = qv;
      }
    }
  __syncthreads();
  if (tid < KNB) {
    float s = redS[tid * 8 + 0] + redS[tid * 8 + 2] + redS[tid * 8 + 4] + redS[tid * 8 + 6];
    float q = redS[tid * 8 + 1] + redS[tid * 8 + 3] + redS[tid * 8 + 5] + redS[tid * 8 + 7];
    float m = s * (1.0f / 128.0f);
    float var = q * (1.0f / 128.0f) - m * m;
    meanL[tid] = m;
    rstdL[tid] = rsqrtf(var + 1e-5f);
  }
  __syncthreads();

  // ---- eln -> f16 (cols 0..127), GEMM2 ----
#pragma unroll
  for (int mt = 0; mt < 3; ++mt)
#pragma unroll
    for (int nt = 0; nt < 2; ++nt) {
      int n = n0 + nt * 16;
      float ls = nt ? ls1 : ls0, lb = nt ? lb1 : lb0;
#pragma unroll
      for (int r = 0; r < 4; ++r) {
        int m = mt * 16 + quad * 4 + r;
        float e = (acc[mt][nt][r] - meanL[m]) * rstdL[m] * ls + lb;
        Ald[m * ASTR + n] = (half_t)e;
      }
    }
  __syncthreads();

  f4 acc2[3][2] = {};
#pragma unroll
  for (int ks = 0; ks < 4; ++ks) {
#pragma unroll
    for (int mt = 0; mt < 3; ++mt) {
      half8 a = *(const half8*)(Ald + (mt * 16 + lm) * ASTR + ks * 32 + quad8);
      acc2[mt][0] = __builtin_amdgcn_mfma_f32_16x16x32_f16(a, b2A[ks], acc2[mt][0], 0, 0, 0);
      acc2[mt][1] = __builtin_amdgcn_mfma_f32_16x16x32_f16(a, b2B[ks], acc2[mt][1], 0, 0, 0);
    }
  }

  // ---- epilogue ----
#pragma unroll
  for (int mt = 0; mt < 3; ++mt)
#pragma unroll
    for (int nt = 0; nt < 2; ++nt) {
      int n = n0 + nt * 16;
      float bp = nt ? bp1 : bp0;
#pragma unroll
      for (int r = 0; r < 4; ++r) {
        int m = mt * 16 + quad * 4 + r;
        out[((size_t)i * KNB + m) * 128 + n] = acc2[mt][nt][r] + bp;
      }
    }
}

extern "C" void kernel_launch(void* const* d_in, const int* in_sizes, int n_in,
                              void* d_out, int out_size, void* d_ws, size_t ws_size,
                              hipStream_t stream) {
  const float* X        = (const float*)d_in[0];
  const float* node_h   = (const float*)d_in[1];
  const float* f_node   = (const float*)d_in[2];
  const float* Wpos     = (const float*)d_in[3];
  const float* bpos     = (const float*)d_in[4];
  const float* We       = (const float*)d_in[5];
  const float* ln_scale = (const float*)d_in[6];
  const float* ln_bias  = (const float*)d_in[7];
  const float* Wproj    = (const float*)d_in[8];
  const float* bproj    = (const float*)d_in[9];
  const int*   aatype   = (const int*)d_in[10];
  const int*   residue_index = (const int*)d_in[11];
  float* out = (float*)d_out;

  char* ws = (char*)d_ws;
  half_t* WeH    = (half_t*)(ws + 3145728);      // 73728 B (layout kept from prior rounds)
  half_t* WpH    = (half_t*)(ws + 3219456);      // 32768 B
  float*  Wh32   = (float*)(ws + 3252224);       // 65536 B
  half_t* WposB  = (half_t*)(ws + 3317760);      // 1024 B
  float*  hbAll  = (float*)(ws + 3318784);       // 4 MB
  half_t* fnH    = (half_t*)(ws + 7513088);      // 2 MB
  half_t* nhH    = (half_t*)(ws + 9610240);      // 2 MB -> total 11707392 B

  setup_a_kernel<<<144, 256, 0, stream>>>(We, Wproj, Wpos, WeH, WpH, Wh32, WposB);
  setup_b_kernel<<<3072, 256, 0, stream>>>(f_node, node_h, Wh32, fnH, nhH, hbAll);
  fused_kernel<<<LRES, 256, 0, stream>>>(X, fnH, nhH, Wpos, bpos, ln_scale,
                                         ln_bias, bproj, aatype, residue_index,
                                         WeH, WpH, WposB, hbAll, out);
}

// Round 9
// 399.129 us; speedup vs baseline: 1.0082x; 1.0082x over previous
//
#include <hip/hip_runtime.h>
#include <stdint.h>
#include <math.h>

#define LRES 8192
#define KNB  48
#define ASTR 296   // f16 row stride for A (148 words: only 2-way bank aliasing = free)
#define CUT  64    // knn: histogram only bins < CUT (16 Angstrom); exact fallback if b* >= CUT-1

typedef _Float16 half_t;
typedef _Float16 half8 __attribute__((ext_vector_type(8)));
typedef float f4 __attribute__((ext_vector_type(4)));

// ---------------- setup_a: weight reorder/convert (writes Wh32) ----------------
// Separate launch from setup_b: hbias reads Wh32; intra-grid block order is undefined (r7 race).
__global__ __launch_bounds__(256) void setup_a_kernel(
    const float* __restrict__ We, const float* __restrict__ Wproj,
    const float* __restrict__ Wpos,
    half_t* __restrict__ WeH, half_t* __restrict__ WpH,
    float* __restrict__ Wh32, half_t* __restrict__ WposB) {
  int t = blockIdx.x * blockDim.x + threadIdx.x;
  if (t < 128 * 288) {
    int n = t / 288, kp = t % 288;
    int k = kp < 160 ? kp : kp + 128;
    WeH[n * 288 + kp] = (half_t)We[n * 416 + k];
  }
  if (t < 128 * 128) {
    int n = t >> 7, k = t & 127;
    WpH[t] = (half_t)Wproj[t];
    Wh32[k * 128 + n] = We[n * 416 + 160 + k];
  }
  if (t < 512) {
    int p = t >> 5, k = t & 31;
    float v = (k < 8) ? Wpos[p * 66 + 32 + k] : ((k < 16) ? 0.0f : Wpos[p * 66 + k]);
    WposB[t] = (half_t)v;
  }
}

// ---------------- setup_b: cvt (f32->f16 copies) + hbias GEMV (reads Wh32) ----------------
__global__ __launch_bounds__(256) void setup_b_kernel(
    const float* __restrict__ f_node, const float* __restrict__ node_h,
    const float* __restrict__ Wh32,
    half_t* __restrict__ fnH, half_t* __restrict__ nhH,
    float* __restrict__ hb) {
  __shared__ float hrow[4][128];
  const int b = blockIdx.x;
  const int tid = threadIdx.x;
  if (b < 1024) {
    int g = b * 256 + tid;
    int sel = g >> 17;
    size_t off = (size_t)(g & 131071) * 8;
    const float* s = sel ? node_h : f_node;
    half_t* d = sel ? nhH : fnH;
    f4 a = *(const f4*)(s + off);
    f4 bb = *(const f4*)(s + off + 4);
    half8 h;
#pragma unroll
    for (int j = 0; j < 4; ++j) { h[j] = (half_t)a[j]; h[4 + j] = (half_t)bb[j]; }
    *(half8*)(d + off) = h;
  } else {
    const int i0 = (b - 1024) * 4;
    for (int u = tid; u < 512; u += 256) hrow[u >> 7][u & 127] = node_h[(size_t)i0 * 128 + u];
    __syncthreads();
    const int n = tid & 127, g = tid >> 7;
    float s0 = 0.f, s1 = 0.f;
#pragma unroll 8
    for (int cc = 0; cc < 128; ++cc) {
      float w = Wh32[cc * 128 + n];
      s0 = fmaf(w, hrow[g][cc], s0);
      s1 = fmaf(w, hrow[g + 2][cc], s1);
    }
    hb[(size_t)(i0 + g) * 128 + n] = s0;
    hb[(size_t)(i0 + g + 2) * 128 + n] = s1;
  }
}

// ---------------- fused kernel: knn (exact top-48) -> edge features + MFMA GEMMs + LN ----------------
// LDS packed to 32768 B -> 5 blocks/CU (was 33280 -> 4). metaL packs j|pidx|aa (13|4|5 bits).
// Histogram scan is a wave-0 shfl prefix-scan (was tid0 serial, ~64 dependent LDS reads).
__global__ __launch_bounds__(256, 4) void fused_kernel(
    const float* __restrict__ X, const half_t* __restrict__ fnH,
    const half_t* __restrict__ nhH, const float* __restrict__ Wpos,
    const float* __restrict__ bpos, const float* __restrict__ ln_scale,
    const float* __restrict__ ln_bias, const float* __restrict__ bproj,
    const int* __restrict__ aatype, const int* __restrict__ residue_index,
    const half_t* __restrict__ WeH, const half_t* __restrict__ WpH,
    const half_t* __restrict__ WposB, const float* __restrict__ hbAll,
    float* __restrict__ out) {
  __shared__ __align__(16) half_t Ald[48 * ASTR];   // 28416 B; bytes [0,3072) alias knn cand arrays
  __shared__ float tabPool[672];   // pos_tab/aa_tab; aliased by redS/mean/rstd after P2
  __shared__ float DkL[48];
  __shared__ int metaL[48];        // sort: plain j; after P0: j | pidx<<13 | aa<<17
  __shared__ unsigned hist[256];
  __shared__ unsigned cnt;
  __shared__ int bstar_s;
  __shared__ unsigned cexp_s;
  __shared__ int needFull_s;

  double* candD = (double*)Ald;              // [256] = 2048 B
  int*    candJ = (int*)(Ald + 1024);        // [256] = 1024 B
  float* pos_tab = tabPool;
  float* aa_tab  = tabPool + 256;
  float* redS    = tabPool;                  // aliases tabs after last tab read (P2)
  float* meanL   = tabPool + 384;
  float* rstdL   = tabPool + 432;

  const int i = blockIdx.x;
  const int tid = threadIdx.x;
  const int w = tid >> 6;
  const int lane = tid & 63;
  const int lm = lane & 15;
  const int quad = lane >> 4;
  const int quad8 = quad * 8;
  const int n0 = w * 32 + lm;

  // ---- weight tables (tabPool region: disjoint from knn's hist/cand) ----
  {
    int pp = tid >> 4, p = tid & 15;
    pos_tab[tid] = Wpos[p * 66 + pp] + bpos[p];
  }
  for (int t = tid; t < 416; t += 256) {
    int a = t >> 4, p = t & 15;
    aa_tab[t] = Wpos[p * 66 + 40 + a];
  }

  // ================= KNN phase =================
  const float xi = X[i * 3 + 0], yi = X[i * 3 + 1], zi = X[i * 3 + 2];
  hist[tid] = 0u;
  if (tid == 0) cnt = 0u;
  __syncthreads();
  unsigned bpack[8];
#pragma unroll
  for (int it = 0; it < 8; ++it) {
    int jb = (tid + it * 256) * 4;
    const float* xp = X + (size_t)jb * 3;
    f4 r0 = *(const f4*)(xp);
    f4 r1 = *(const f4*)(xp + 4);
    f4 r2 = *(const f4*)(xp + 8);
    float px[4] = {r0[0], r0[3], r1[2], r2[1]};
    float py[4] = {r0[1], r1[0], r1[3], r2[2]};
    float pz[4] = {r0[2], r1[1], r2[0], r2[3]};
#pragma unroll
    for (int q = 0; q < 4; ++q) {
      float dx = px[q] - xi, dy = py[q] - yi, dz = pz[q] - zi;
      float D = sqrtf(dx * dx + dy * dy + dz * dz + 1e-6f);
      int b = (int)(D * 4.0f); if (b > 255) b = 255;
      int idx = it * 4 + q;
      int sh = (idx & 3) * 8;
      if ((idx & 3) == 0) bpack[idx >> 2] = (unsigned)b; else bpack[idx >> 2] |= (unsigned)b << sh;
      if (b < CUT) atomicAdd(&hist[b], 1u);
    }
  }
  __syncthreads();
  // wave-0 parallel prefix-scan over bins 0..63 (common case b* < CUT-1)
  if (tid < 64) {
    int pre = (int)hist[tid];
#pragma unroll
    for (int s = 1; s < 64; s <<= 1) {
      int t = __shfl_up(pre, s, 64);
      if (tid >= s) pre += t;
    }
    unsigned long long m = __ballot(pre >= KNB);
    int bs = m ? (int)__builtin_ctzll(m) : 64;
    if (bs >= CUT - 1) {
      if (tid == 0) needFull_s = 1;
    } else {
      if (tid == 0) { bstar_s = bs; needFull_s = 0; }
      if (tid == bs + 1) cexp_s = (unsigned)pre;   // count through bin bthr = bs+1
    }
  }
  __syncthreads();
  if (needFull_s) {           // rare: complete the histogram exactly, serial rescan
#pragma unroll
    for (int idx = 0; idx < 32; ++idx) {
      int b = (int)((bpack[idx >> 2] >> ((idx & 3) * 8)) & 0xFFu);
      if (b >= CUT) atomicAdd(&hist[b], 1u);
    }
    __syncthreads();
    if (tid == 0) {
      unsigned run = 0; int b = 0;
      while (b < 255 && run + hist[b] < KNB) { run += hist[b]; ++b; }
      bstar_s = b;
      unsigned tot = run + hist[b];
      if (b < 255) tot += hist[b + 1];
      cexp_s = tot;
    }
    __syncthreads();
  }
  int bthr = bstar_s + 1; if (bthr > 255) bthr = 255;  // +1 bin slack covers fp32 vs fp64
  const unsigned cexp = cexp_s;
  const double xid = (double)xi, yid = (double)yi, zid = (double)zi;
  // pass 2: candidate mask from cached bins, rolled fp64-key collection
  {
    unsigned cmask = 0u;
#pragma unroll
    for (int idx = 0; idx < 32; ++idx) {
      int b = (int)((bpack[idx >> 2] >> ((idx & 3) * 8)) & 0xFFu);
      if (b <= bthr) cmask |= (1u << idx);
    }
    while (cmask) {
      int k = __builtin_ctz(cmask);
      cmask &= cmask - 1u;
      int j = (tid + (k >> 2) * 256) * 4 + (k & 3);
      unsigned p = atomicAdd(&cnt, 1u);
      if (p < 256u) {
        double ddx = (double)X[j * 3 + 0] - xid;
        double ddy = (double)X[j * 3 + 1] - yid;
        double ddz = (double)X[j * 3 + 2] - zid;
        candD[p] = sqrt(ddx * ddx + ddy * ddy + ddz * ddz + 1e-6);
        candJ[p] = j;
      }
    }
  }
  __syncthreads();
  unsigned nc = cnt;
  if (cexp <= 64u) {
    // common path: wave-0 register bitonic over 64 (double,int) keys -> metaL/DkL
    if (tid < 64) {
      double d = (tid < (int)nc) ? candD[tid] : INFINITY;
      int j = (tid < (int)nc) ? candJ[tid] : 0x7FFFFFFF;
#pragma unroll
      for (int size = 2; size <= 64; size <<= 1) {
#pragma unroll
        for (int stride = 32; stride > 0; stride >>= 1) {
          if (stride >= size) continue;
          double dp = __shfl_xor(d, stride, 64);
          int jp = __shfl_xor(j, stride, 64);
          bool up = ((tid & size) == 0);
          bool lower = ((tid & stride) == 0);
          bool mine_gt = (d > dp) || (d == dp && j > jp);
          bool part_gt = (dp > d) || (dp == d && jp > j);
          bool keep = lower ? (mine_gt != up) : (part_gt != up);
          d = keep ? d : dp;
          j = keep ? j : jp;
        }
      }
      if (tid < KNB) { metaL[tid] = j; DkL[tid] = (float)d; }
    }
  } else {
    // fallback (count in (64,256]): 256-way LDS bitonic (block-uniform branch)
    if (tid >= (int)nc) { candD[tid] = INFINITY; candJ[tid] = 0x7FFFFFFF; }
    __syncthreads();
    for (unsigned size = 2; size <= 256; size <<= 1) {
      for (unsigned stride = size >> 1; stride > 0; stride >>= 1) {
        unsigned partner = (unsigned)tid ^ stride;
        if (partner > (unsigned)tid) {
          double da = candD[tid], db = candD[partner];
          int ja = candJ[tid], jb = candJ[partner];
          bool agtb = (da > db) || (da == db && ja > jb);
          bool asc = ((tid & size) == 0);
          if (agtb == asc) {
            candD[tid] = db; candJ[tid] = jb;
            candD[partner] = da; candJ[partner] = ja;
          }
        }
        __syncthreads();
      }
    }
    if (tid < KNB) { metaL[tid] = candJ[tid]; DkL[tid] = (float)candD[tid]; }
  }
  __syncthreads();   // knn results extracted; Ald (incl. cand alias region) free for edge

  // ================= EDGE phase =================
  // ---- P0: per-edge scalars; geom into Ald cols 128..135 (f16); pack pidx/aa into metaL ----
  if (tid < KNB) {
    int e = tid;
    int j = metaL[e] & 8191;
    float Dk = DkL[e];
    float xj = X[j * 3 + 0], yj = X[j * 3 + 1], zj = X[j * 3 + 2];
    float inv = 1.0f / (Dk + 1e-6f);
    half_t* gr = Ald + e * ASTR + 128;
    gr[0] = (half_t)(Dk / 10.0f);
    gr[1] = (half_t)(1.0f / (1.0f + Dk));
    gr[2] = (half_t)expf(-Dk);
    gr[3] = (half_t)sinf(Dk);
    gr[4] = (half_t)cosf(Dk);
    gr[5] = (half_t)((xj - xi) * inv);
    gr[6] = (half_t)((yj - yi) * inv);
    gr[7] = (half_t)((zj - zi) * inv);
    // cols 136..143 MUST be zeroed: B rows 8..15 are zero, but 0*NaN-garbage = NaN in MFMA.
    *(uint2*)(gr + 8)  = (uint2){0u, 0u};
    *(uint2*)(gr + 12) = (uint2){0u, 0u};
    int off = residue_index[j] - residue_index[i] + 8;
    off = off < 0 ? 0 : (off > 15 ? 15 : off);
    metaL[e] = j | (off << 13) | (aatype[j] << 17);
  }
  __syncthreads();

  // ---- P1: rbf (cols 144..159) + half8 gathers fnH->0..127, nhH->160..287 ----
  for (int t = tid; t < KNB * 16; t += 256) {
    int e = t >> 4, m = t & 15;
    float z = (DkL[e] - (2.0f + (float)m * (20.0f / 15.0f))) * 0.8f;
    Ald[e * ASTR + 144 + m] = (half_t)expf(-z * z);
  }
#pragma unroll
  for (int it = 0; it < 6; ++it) {
    int cid = tid + it * 256;
    int e = cid >> 5, r = cid & 31;
    int sel = r >> 4, c8 = r & 15;
    const half_t* src = (sel ? nhH : fnH) + (size_t)(metaL[e] & 8191) * 128 + c8 * 8;
    *(half8*)(Ald + e * ASTR + sel * 160 + c8 * 8) = *(const half8*)src;
  }
  // prefetch GEMM1 B + h_i bias; latency hidden under gathers/P2
  half8 bregA[9], bregB[9];
#pragma unroll
  for (int ks = 0; ks < 9; ++ks) {
    bregA[ks] = *(const half8*)(WeH + (size_t)n0 * 288 + ks * 32 + quad8);
    bregB[ks] = *(const half8*)(WeH + (size_t)(n0 + 16) * 288 + ks * 32 + quad8);
  }
  float hb0 = hbAll[(size_t)i * 128 + n0];
  float hb1 = hbAll[(size_t)i * 128 + n0 + 16];
  __syncthreads();

  // ---- P2: e_pos via single MFMA per wave + table adds ----
  if (w < 3) {
    half8 a = *(const half8*)(Ald + (w * 16 + lm) * ASTR + 128 + quad8);
    half8 bp = *(const half8*)(WposB + lm * 32 + quad8);
    f4 z = {};
    f4 ep = __builtin_amdgcn_mfma_f32_16x16x32_f16(a, bp, z, 0, 0, 0);
#pragma unroll
    for (int r = 0; r < 4; ++r) {
      int m = w * 16 + quad * 4 + r;
      int mm = metaL[m];
      float s = ep[r] + pos_tab[((mm >> 13) & 15) * 16 + lm] + aa_tab[((mm >> 17) & 31) * 16 + lm];
      Ald[m * ASTR + 128 + lm] = (half_t)s;
    }
  }
  __syncthreads();

  // ---- GEMM1 ----
  f4 acc[3][2] = {};
#pragma unroll
  for (int ks = 0; ks < 9; ++ks) {
#pragma unroll
    for (int mt = 0; mt < 3; ++mt) {
      half8 a = *(const half8*)(Ald + (mt * 16 + lm) * ASTR + ks * 32 + quad8);
      acc[mt][0] = __builtin_amdgcn_mfma_f32_16x16x32_f16(a, bregA[ks], acc[mt][0], 0, 0, 0);
      acc[mt][1] = __builtin_amdgcn_mfma_f32_16x16x32_f16(a, bregB[ks], acc[mt][1], 0, 0, 0);
    }
  }
  // prefetch GEMM2 B + LN/proj params; latency hidden under LN reduce
  half8 b2A[4], b2B[4];
#pragma unroll
  for (int ks = 0; ks < 4; ++ks) {
    b2A[ks] = *(const half8*)(WpH + (size_t)n0 * 128 + ks * 32 + quad8);
    b2B[ks] = *(const half8*)(WpH + (size_t)(n0 + 16) * 128 + ks * 32 + quad8);
  }
  float ls0 = ln_scale[n0], ls1 = ln_scale[n0 + 16];
  float lb0 = ln_bias[n0],  lb1 = ln_bias[n0 + 16];
  float bp0 = bproj[n0],    bp1 = bproj[n0 + 16];

  // ---- h_i bias + LN partials ----
#pragma unroll
  for (int mt = 0; mt < 3; ++mt)
#pragma unroll
    for (int r = 0; r < 4; ++r) { acc[mt][0][r] += hb0; acc[mt][1][r] += hb1; }
#pragma unroll
  for (int mt = 0; mt < 3; ++mt)
#pragma unroll
    for (int r = 0; r < 4; ++r) {
      float e0 = acc[mt][0][r], e1 = acc[mt][1][r];
      float sv = e0 + e1;
      float qv = e0 * e0 + e1 * e1;
#pragma unroll
      for (int m = 1; m < 16; m <<= 1) {
        sv += __shfl_xor(sv, m, 16);
        qv += __shfl_xor(qv, m, 16);
      }
      if (lm == 0) {
        int row = mt * 16 + quad * 4 + r;
        redS[row * 8 + w * 2 + 0] = sv;
        redS[row * 8 + w * 2 + 1] = qv;
      }
    }
  __syncthreads();
  if (tid < KNB) {
    float s = redS[tid * 8 + 0] + redS[tid * 8 + 2] + redS[tid * 8 + 4] + redS[tid * 8 + 6];
    float q = redS[tid * 8 + 1] + redS[tid * 8 + 3] + redS[tid * 8 + 5] + redS[tid * 8 + 7];
    float m = s * (1.0f / 128.0f);
    float var = q * (1.0f / 128.0f) - m * m;
    meanL[tid] = m;
    rstdL[tid] = rsqrtf(var + 1e-5f);
  }
  __syncthreads();

  // ---- eln -> f16 (cols 0..127), GEMM2 ----
#pragma unroll
  for (int mt = 0; mt < 3; ++mt)
#pragma unroll
    for (int nt = 0; nt < 2; ++nt) {
      int n = n0 + nt * 16;
      float ls = nt ? ls1 : ls0, lb = nt ? lb1 : lb0;
#pragma unroll
      for (int r = 0; r < 4; ++r) {
        int m = mt * 16 + quad * 4 + r;
        float e = (acc[mt][nt][r] - meanL[m]) * rstdL[m] * ls + lb;
        Ald[m * ASTR + n] = (half_t)e;
      }
    }
  __syncthreads();

  f4 acc2[3][2] = {};
#pragma unroll
  for (int ks = 0; ks < 4; ++ks) {
#pragma unroll
    for (int mt = 0; mt < 3; ++mt) {
      half8 a = *(const half8*)(Ald + (mt * 16 + lm) * ASTR + ks * 32 + quad8);
      acc2[mt][0] = __builtin_amdgcn_mfma_f32_16x16x32_f16(a, b2A[ks], acc2[mt][0], 0, 0, 0);
      acc2[mt][1] = __builtin_amdgcn_mfma_f32_16x16x32_f16(a, b2B[ks], acc2[mt][1], 0, 0, 0);
    }
  }

  // ---- epilogue ----
#pragma unroll
  for (int mt = 0; mt < 3; ++mt)
#pragma unroll
    for (int nt = 0; nt < 2; ++nt) {
      int n = n0 + nt * 16;
      float bp = nt ? bp1 : bp0;
#pragma unroll
      for (int r = 0; r < 4; ++r) {
        int m = mt * 16 + quad * 4 + r;
        out[((size_t)i * KNB + m) * 128 + n] = acc2[mt][nt][r] + bp;
      }
    }
}

extern "C" void kernel_launch(void* const* d_in, const int* in_sizes, int n_in,
                              void* d_out, int out_size, void* d_ws, size_t ws_size,
                              hipStream_t stream) {
  const float* X        = (const float*)d_in[0];
  const float* node_h   = (const float*)d_in[1];
  const float* f_node   = (const float*)d_in[2];
  const float* Wpos     = (const float*)d_in[3];
  const float* bpos     = (const float*)d_in[4];
  const float* We       = (const float*)d_in[5];
  const float* ln_scale = (const float*)d_in[6];
  const float* ln_bias  = (const float*)d_in[7];
  const float* Wproj    = (const float*)d_in[8];
  const float* bproj    = (const float*)d_in[9];
  const int*   aatype   = (const int*)d_in[10];
  const int*   residue_index = (const int*)d_in[11];
  float* out = (float*)d_out;

  char* ws = (char*)d_ws;
  half_t* WeH    = (half_t*)(ws + 3145728);      // 73728 B (layout kept from prior rounds)
  half_t* WpH    = (half_t*)(ws + 3219456);      // 32768 B
  float*  Wh32   = (float*)(ws + 3252224);       // 65536 B
  half_t* WposB  = (half_t*)(ws + 3317760);      // 1024 B
  float*  hbAll  = (float*)(ws + 3318784);       // 4 MB
  half_t* fnH    = (half_t*)(ws + 7513088);      // 2 MB
  half_t* nhH    = (half_t*)(ws + 9610240);      // 2 MB -> total 11707392 B

  setup_a_kernel<<<144, 256, 0, stream>>>(We, Wproj, Wpos, WeH, WpH, Wh32, WposB);
  setup_b_kernel<<<3072, 256, 0, stream>>>(f_node, node_h, Wh32, fnH, nhH, hbAll);
  fused_kernel<<<LRES, 256, 0, stream>>>(X, fnH, nhH, Wpos, bpos, ln_scale,
                                         ln_bias, bproj, aatype, residue_index,
                                         WeH, WpH, WposB, hbAll, out);
}